// Round 5
// baseline (351.393 us; speedup 1.0000x reference)
//
#include <hip/hip_runtime.h>
#include <hip/hip_bf16.h>

// GraphSAGE 2-layer + linear head, N=100000, d=h=128, E=640000.
// R5: aggregation fused INTO the GEMM (gather -> LDS As128 -> MFMA);
//     agbf intermediate eliminated; count fused into prep; deg+cursor
//     share one memset. Pipeline: memset, prep+count, offsets, scatter,
//     fused_layer1, fused_layer2+head  (6 dispatches total).

#define ND 128          // feature dim
#define KTOT 256        // concat K ([agg | self])
#define ASTRIDE 40      // chunk stride: 32 + 8 pad (shorts), 80 B
#define FSTRIDE 136     // As128 stride: 128 + 8 pad (shorts), 272 B = 17*16

typedef __bf16 bf16x8 __attribute__((ext_vector_type(8)));
typedef float floatx16 __attribute__((ext_vector_type(16)));

__device__ inline unsigned short f2bf(float f) {
    union { float f; unsigned u; } v; v.f = f;
    unsigned r = v.u + 0x7fffu + ((v.u >> 16) & 1u);   // RTNE
    return (unsigned short)(r >> 16);
}
__device__ inline float bf_lo(unsigned u) { return __uint_as_float(u << 16); }
__device__ inline float bf_hi(unsigned u) { return __uint_as_float(u & 0xffff0000u); }

// ---------------- CSR: offsets (wave prefix scan, one atomic per wave) ----------------
__global__ void k_offsets(const int* __restrict__ deg, int* __restrict__ start,
                          int* __restrict__ fill, int* __restrict__ cursor, int n) {
    int i = blockIdx.x * blockDim.x + threadIdx.x;
    int lane = threadIdx.x & 63;
    int d = (i < n) ? deg[i] : 0;
    int v = d;
#pragma unroll
    for (int off = 1; off < 64; off <<= 1) {
        int t = __shfl_up(v, off);
        if (lane >= off) v += t;
    }
    int total = __shfl(v, 63);
    int base = 0;
    if (lane == 0) base = atomicAdd(cursor, total);
    base = __shfl(base, 0);
    if (i < n) {
        int s = base + v - d;   // exclusive
        start[i] = s;
        fill[i] = s;
    }
}

__global__ void k_scatter(const int* __restrict__ src, const int* __restrict__ dst,
                          int* __restrict__ fill, int* __restrict__ esrc, int E) {
    int e = blockIdx.x * blockDim.x + threadIdx.x;
    if (e < E) {
        int p = atomicAdd(&fill[dst[e]], 1);
        esrc[p] = src[e];
    }
}

// ---------------- merged prep: x->bf16 | Wt1 | Wt2 | degree count ----------------
__global__ void k_prep_count(const float* __restrict__ x, unsigned short* __restrict__ xbf,
                             int nElems, int xBlocks,
                             const float* __restrict__ W1l, const float* __restrict__ W1r,
                             unsigned short* __restrict__ Wt1,
                             const float* __restrict__ W2l, const float* __restrict__ W2r,
                             unsigned short* __restrict__ Wt2,
                             const int* __restrict__ edst, int* __restrict__ deg, int E) {
    int b = blockIdx.x;
    if (b < xBlocks) {
        int i = (b * 256 + threadIdx.x) * 8;
        if (i >= nElems) return;
        float4 a = *(const float4*)(x + i);
        float4 c = *(const float4*)(x + i + 4);
        uint4 r;
        r.x = (unsigned)f2bf(a.x) | ((unsigned)f2bf(a.y) << 16);
        r.y = (unsigned)f2bf(a.z) | ((unsigned)f2bf(a.w) << 16);
        r.z = (unsigned)f2bf(c.x) | ((unsigned)f2bf(c.y) << 16);
        r.w = (unsigned)f2bf(c.z) | ((unsigned)f2bf(c.w) << 16);
        *(uint4*)(xbf + i) = r;
    } else if (b < xBlocks + 256) {
        int wb = b - xBlocks;
        const float* Wl = (wb < 128) ? W1l : W2l;
        const float* Wr = (wb < 128) ? W1r : W2r;
        unsigned short* Wt = (wb < 128) ? Wt1 : Wt2;
        int idx = (wb & 127) * 256 + threadIdx.x;   // 0..32767
        int nn = idx >> 8;       // output col
        int kk = idx & 255;      // concat K
        float v = (kk < 128) ? Wl[(size_t)kk * ND + nn] : Wr[(size_t)(kk - 128) * ND + nn];
        Wt[(size_t)nn * KTOT + kk] = f2bf(v);
    } else {
        int e = (b - xBlocks - 256) * 256 + threadIdx.x;
        if (e < E) atomicAdd(&deg[edst[e]], 1);
    }
}

// ---------------- fused gather + MFMA GEMM core (macro-free via template flag) ----------------
// Phase A: 16 lanes/node gather mean(feat[neighbors]) -> As128[nl][0..127] (bf16).
// Phase B: K=256 GEMM; k<128 fragments straight from As128, k>=128 staged from self.
template <int DO_HEAD>
__launch_bounds__(256, 2)
__global__ void k_fused_layer(const unsigned short* __restrict__ feat,   // gather source + self
                              const unsigned short* __restrict__ Wt,
                              const float* __restrict__ bias,
                              const int* __restrict__ start, const int* __restrict__ deg,
                              const int* __restrict__ esrc,
                              unsigned short* __restrict__ outbf,        // layer-1 output
                              const float* __restrict__ Wlin,
                              const float* __restrict__ blin,
                              float* __restrict__ outf,                  // head output
                              int n) {
    __shared__ __align__(16) unsigned short As128[128 * FSTRIDE];  // 34.8 KB
    __shared__ __align__(16) unsigned short Asc[128 * ASTRIDE];    // 10.2 KB
    __shared__ __align__(16) unsigned short Bs[128 * ASTRIDE];     // 10.2 KB
    __shared__ float part[128][2];

    const int t = threadIdx.x;
    const int m0 = blockIdx.x * 128;
    const int wave = t >> 6, lane = t & 63;
    const int l31 = lane & 31, lhalf = lane >> 5;
    const int wm = (wave >> 1) * 64;
    const int wn = (wave & 1) * 64;

    // ---------- Phase A: gather ----------
    {
        const int g = t >> 4;       // 16-lane group 0..15
        const int l16 = t & 15;
        for (int i = 0; i < 8; ++i) {
            const int nl = g * 8 + i;
            const int grow = m0 + nl;
            float A0 = 0, A1 = 0, A2 = 0, A3 = 0, A4 = 0, A5 = 0, A6 = 0, A7 = 0;
            float C0 = 0, C1 = 0, C2 = 0, C3 = 0, C4 = 0, C5 = 0, C6 = 0, C7 = 0;
            float inv = 1.0f;
            if (grow < n) {
                const int s = start[grow];
                const int d = deg[grow];
                inv = 1.0f / (float)max(d, 1);
                int j = 0;
                for (; j + 4 <= d; j += 4) {
                    int s0 = esrc[s + j], s1 = esrc[s + j + 1];
                    int s2 = esrc[s + j + 2], s3 = esrc[s + j + 3];
                    uint4 v0 = ((const uint4*)(feat + (size_t)s0 * ND))[l16];
                    uint4 v1 = ((const uint4*)(feat + (size_t)s1 * ND))[l16];
                    uint4 v2 = ((const uint4*)(feat + (size_t)s2 * ND))[l16];
                    uint4 v3 = ((const uint4*)(feat + (size_t)s3 * ND))[l16];
                    A0 += bf_lo(v0.x); A1 += bf_hi(v0.x); A2 += bf_lo(v0.y); A3 += bf_hi(v0.y);
                    A4 += bf_lo(v0.z); A5 += bf_hi(v0.z); A6 += bf_lo(v0.w); A7 += bf_hi(v0.w);
                    C0 += bf_lo(v1.x); C1 += bf_hi(v1.x); C2 += bf_lo(v1.y); C3 += bf_hi(v1.y);
                    C4 += bf_lo(v1.z); C5 += bf_hi(v1.z); C6 += bf_lo(v1.w); C7 += bf_hi(v1.w);
                    A0 += bf_lo(v2.x); A1 += bf_hi(v2.x); A2 += bf_lo(v2.y); A3 += bf_hi(v2.y);
                    A4 += bf_lo(v2.z); A5 += bf_hi(v2.z); A6 += bf_lo(v2.w); A7 += bf_hi(v2.w);
                    C0 += bf_lo(v3.x); C1 += bf_hi(v3.x); C2 += bf_lo(v3.y); C3 += bf_hi(v3.y);
                    C4 += bf_lo(v3.z); C5 += bf_hi(v3.z); C6 += bf_lo(v3.w); C7 += bf_hi(v3.w);
                }
                for (; j < d; ++j) {
                    int s0 = esrc[s + j];
                    uint4 v0 = ((const uint4*)(feat + (size_t)s0 * ND))[l16];
                    A0 += bf_lo(v0.x); A1 += bf_hi(v0.x); A2 += bf_lo(v0.y); A3 += bf_hi(v0.y);
                    A4 += bf_lo(v0.z); A5 += bf_hi(v0.z); A6 += bf_lo(v0.w); A7 += bf_hi(v0.w);
                }
            }
            A0 += C0; A1 += C1; A2 += C2; A3 += C3;
            A4 += C4; A5 += C5; A6 += C6; A7 += C7;
            uint4 r;
            r.x = (unsigned)f2bf(A0 * inv) | ((unsigned)f2bf(A1 * inv) << 16);
            r.y = (unsigned)f2bf(A2 * inv) | ((unsigned)f2bf(A3 * inv) << 16);
            r.z = (unsigned)f2bf(A4 * inv) | ((unsigned)f2bf(A5 * inv) << 16);
            r.w = (unsigned)f2bf(A6 * inv) | ((unsigned)f2bf(A7 * inv) << 16);
            *(uint4*)&As128[nl * FSTRIDE + l16 * 8] = r;
        }
    }

    floatx16 acc[2][2];
#pragma unroll
    for (int i = 0; i < 2; ++i)
#pragma unroll
        for (int j = 0; j < 2; ++j) acc[i][j] = (floatx16)0.0f;

    const int srow = t >> 1;           // staging row 0..127
    const int skid = (t & 1) * 16;     // staging k offset 0/16

    __syncthreads();

    // ---------- Phase B: K-loop ----------
    for (int kc = 0; kc < 8; ++kc) {
        const int k0 = kc * 32;
        if (kc >= 4) {
            // stage self chunk from feat rows [m0..m0+128), cols k0-128..+32
            const int col = (k0 - 128) + skid;
            const int grow = m0 + srow;
            int4 w0 = {0, 0, 0, 0}, w1 = {0, 0, 0, 0};
            if (grow < n) {
                const int4* p = (const int4*)(feat + (size_t)grow * ND + col);
                w0 = p[0]; w1 = p[1];
            }
            int4* q = (int4*)&Asc[srow * ASTRIDE + skid];
            q[0] = w0; q[1] = w1;
        }
        {
            const int4* p = (const int4*)(Wt + (size_t)srow * KTOT + k0 + skid);
            int4* q = (int4*)&Bs[srow * ASTRIDE + skid];
            q[0] = p[0]; q[1] = p[1];
        }
        __syncthreads();
        bf16x8 af[2][2], bfr[2][2];
#pragma unroll
        for (int mi = 0; mi < 2; ++mi)
#pragma unroll
            for (int ks = 0; ks < 2; ++ks) {
                const int row = wm + mi * 32 + l31;
                af[mi][ks] = (kc < 4)
                    ? *(const bf16x8*)&As128[row * FSTRIDE + k0 + ks * 16 + lhalf * 8]
                    : *(const bf16x8*)&Asc[row * ASTRIDE + ks * 16 + lhalf * 8];
            }
#pragma unroll
        for (int ni = 0; ni < 2; ++ni)
#pragma unroll
            for (int ks = 0; ks < 2; ++ks)
                bfr[ni][ks] = *(const bf16x8*)&Bs[(wn + ni * 32 + l31) * ASTRIDE + ks * 16 + lhalf * 8];
#pragma unroll
        for (int mi = 0; mi < 2; ++mi)
#pragma unroll
            for (int ni = 0; ni < 2; ++ni) {
                acc[mi][ni] = __builtin_amdgcn_mfma_f32_32x32x16_bf16(af[mi][0], bfr[ni][0], acc[mi][ni], 0, 0, 0);
                acc[mi][ni] = __builtin_amdgcn_mfma_f32_32x32x16_bf16(af[mi][1], bfr[ni][1], acc[mi][ni], 0, 0, 0);
            }
        __syncthreads();
    }

    // ---------- epilogue ----------
    // C/D layout: col=lane&31, row=(reg&3)+8*(reg>>2)+4*(lane>>5)
    if (DO_HEAD == 0) {
#pragma unroll
        for (int mi = 0; mi < 2; ++mi)
#pragma unroll
            for (int ni = 0; ni < 2; ++ni) {
                const int c = wn + ni * 32 + l31;
                const float bv = bias[c];
#pragma unroll
                for (int reg = 0; reg < 16; ++reg) {
                    const int row = m0 + wm + mi * 32 + lhalf * 4 + (reg & 3) + 8 * (reg >> 2);
                    if (row < n) {
                        float v = fmaxf(acc[mi][ni][reg] + bv, 0.f);
                        outbf[(size_t)row * ND + c] = f2bf(v);
                    }
                }
            }
    } else {
#pragma unroll
        for (int mi = 0; mi < 2; ++mi) {
            float p[16];
#pragma unroll
            for (int reg = 0; reg < 16; ++reg) p[reg] = 0.f;
#pragma unroll
            for (int ni = 0; ni < 2; ++ni) {
                const int c = wn + ni * 32 + l31;
                const float bv = bias[c];
                const float wv = Wlin[c];
#pragma unroll
                for (int reg = 0; reg < 16; ++reg) {
                    float v = fmaxf(acc[mi][ni][reg] + bv, 0.f);
                    p[reg] += v * wv;
                }
            }
#pragma unroll
            for (int reg = 0; reg < 16; ++reg) {
                float v = p[reg];
                v += __shfl_xor(v, 1);
                v += __shfl_xor(v, 2);
                v += __shfl_xor(v, 4);
                v += __shfl_xor(v, 8);
                v += __shfl_xor(v, 16);
                if (l31 == 0) {
                    int rl = wm + mi * 32 + lhalf * 4 + (reg & 3) + 8 * (reg >> 2);
                    part[rl][wave & 1] = v;
                }
            }
        }
        __syncthreads();
        if (t < 128) {
            int row = m0 + t;
            if (row < n) outf[row] = part[t][0] + part[t][1] + blin[0];
        }
    }
}

extern "C" void kernel_launch(void* const* d_in, const int* in_sizes, int n_in,
                              void* d_out, int out_size, void* d_ws, size_t ws_size,
                              hipStream_t stream) {
    const float* x    = (const float*)d_in[0];
    const int*   edge = (const int*)d_in[1];    // [2, E]
    const float* W1l  = (const float*)d_in[2];
    const float* b1   = (const float*)d_in[3];
    const float* W1r  = (const float*)d_in[4];
    const float* W2l  = (const float*)d_in[5];
    const float* b2   = (const float*)d_in[6];
    const float* W2r  = (const float*)d_in[7];
    const float* Wlin = (const float*)d_in[8];
    const float* blin = (const float*)d_in[9];
    float* out = (float*)d_out;

    int n = out_size;               // 100000 nodes
    int E = in_sizes[1] / 2;        // 640000 edges
    (void)n_in; (void)ws_size;

    char* ws = (char*)d_ws;
    size_t off = 0;
    auto take = [&](size_t bytes) -> char* {
        char* p = ws + off;
        off += (bytes + 255) & ~(size_t)255;
        return p;
    };
    int* deg    = (int*)take((size_t)n * 4 + 256);   // cursor rides at deg[n]
    int* cursor = deg + n;
    int* start  = (int*)take((size_t)n * 4);
    int* fill   = (int*)take((size_t)n * 4);
    int* esrc   = (int*)take((size_t)E * 4);
    unsigned short* xbf  = (unsigned short*)take((size_t)n * ND * 2);
    unsigned short* h1bf = (unsigned short*)take((size_t)n * ND * 2);
    unsigned short* Wt1  = (unsigned short*)take((size_t)ND * KTOT * 2);
    unsigned short* Wt2  = (unsigned short*)take((size_t)ND * KTOT * 2);

    hipMemsetAsync(deg, 0, (size_t)n * 4 + 4, stream);   // deg + cursor in one fill

    const int* esrc_in = edge;       // row 0: src
    const int* edst_in = edge + E;   // row 1: dst

    int xBlocks = (n * ND / 8 + 255) / 256;
    int cntBlocks = (E + 255) / 256;

    k_prep_count<<<xBlocks + 256 + cntBlocks, 256, 0, stream>>>(
        x, xbf, n * ND, xBlocks, W1l, W1r, Wt1, W2l, W2r, Wt2, edst_in, deg, E);
    k_offsets<<<(n + 255) / 256, 256, 0, stream>>>(deg, start, fill, cursor, n);
    k_scatter<<<(E + 255) / 256, 256, 0, stream>>>(esrc_in, edst_in, fill, esrc, E);

    int gemmBlocks = (n + 127) / 128;

    // layer 1: gather(xbf) + GEMM -> h1bf
    k_fused_layer<0><<<gemmBlocks, 256, 0, stream>>>(
        xbf, Wt1, b1, start, deg, esrc, h1bf, nullptr, nullptr, nullptr, n);
    // layer 2: gather(h1bf) + GEMM + head -> out
    k_fused_layer<1><<<gemmBlocks, 256, 0, stream>>>(
        h1bf, Wt2, b2, start, deg, esrc, nullptr, Wlin, blin, out, n);
}

// Round 6
// 281.700 us; speedup vs baseline: 1.2474x; 1.2474x over previous
//
#include <hip/hip_runtime.h>
#include <hip/hip_bf16.h>

// GraphSAGE 2-layer + linear head, N=100000, d=h=128, E=640000.
// R6: revert R5 fusion (gather needs occupancy, GEMM needs LDS — split wins).
//     Aggregate: 16 lanes/node, chunk-of-4 neighbor loads with clamped
//     indices + zero masking (no scalar tail, 4 rows always in flight).
//     Pipeline: memset, prep+count, offsets, scatter, agg1, gemm1, agg2,
//     gemm2+head = 8 dispatches.

#define ND 128          // feature dim
#define KTOT 256        // concat K ([agg | self])
#define ASTRIDE 40      // 32 + 8 pad (shorts)

typedef __bf16 bf16x8 __attribute__((ext_vector_type(8)));
typedef float floatx16 __attribute__((ext_vector_type(16)));

__device__ inline unsigned short f2bf(float f) {
    union { float f; unsigned u; } v; v.f = f;
    unsigned r = v.u + 0x7fffu + ((v.u >> 16) & 1u);   // RTNE
    return (unsigned short)(r >> 16);
}
__device__ inline float bf_lo(unsigned u) { return __uint_as_float(u << 16); }
__device__ inline float bf_hi(unsigned u) { return __uint_as_float(u & 0xffff0000u); }

// ---------------- CSR: offsets (wave prefix scan, one atomic per wave) ----------------
__global__ void k_offsets(const int* __restrict__ deg, int* __restrict__ start,
                          int* __restrict__ fill, int* __restrict__ cursor, int n) {
    int i = blockIdx.x * blockDim.x + threadIdx.x;
    int lane = threadIdx.x & 63;
    int d = (i < n) ? deg[i] : 0;
    int v = d;
#pragma unroll
    for (int off = 1; off < 64; off <<= 1) {
        int t = __shfl_up(v, off);
        if (lane >= off) v += t;
    }
    int total = __shfl(v, 63);
    int base = 0;
    if (lane == 0) base = atomicAdd(cursor, total);
    base = __shfl(base, 0);
    if (i < n) {
        int s = base + v - d;   // exclusive
        start[i] = s;
        fill[i] = s;
    }
}

__global__ void k_scatter(const int* __restrict__ src, const int* __restrict__ dst,
                          int* __restrict__ fill, int* __restrict__ esrc, int E) {
    int e = blockIdx.x * blockDim.x + threadIdx.x;
    if (e < E) {
        int p = atomicAdd(&fill[dst[e]], 1);
        esrc[p] = src[e];
    }
}

// ---------------- merged prep: x->bf16 | Wt1 | Wt2 | degree count ----------------
__global__ void k_prep_count(const float* __restrict__ x, unsigned short* __restrict__ xbf,
                             int nElems, int xBlocks,
                             const float* __restrict__ W1l, const float* __restrict__ W1r,
                             unsigned short* __restrict__ Wt1,
                             const float* __restrict__ W2l, const float* __restrict__ W2r,
                             unsigned short* __restrict__ Wt2,
                             const int* __restrict__ edst, int* __restrict__ deg, int E) {
    int b = blockIdx.x;
    if (b < xBlocks) {
        int i = (b * 256 + threadIdx.x) * 8;
        if (i >= nElems) return;
        float4 a = *(const float4*)(x + i);
        float4 c = *(const float4*)(x + i + 4);
        uint4 r;
        r.x = (unsigned)f2bf(a.x) | ((unsigned)f2bf(a.y) << 16);
        r.y = (unsigned)f2bf(a.z) | ((unsigned)f2bf(a.w) << 16);
        r.z = (unsigned)f2bf(c.x) | ((unsigned)f2bf(c.y) << 16);
        r.w = (unsigned)f2bf(c.z) | ((unsigned)f2bf(c.w) << 16);
        *(uint4*)(xbf + i) = r;
    } else if (b < xBlocks + 256) {
        int wb = b - xBlocks;
        const float* Wl = (wb < 128) ? W1l : W2l;
        const float* Wr = (wb < 128) ? W1r : W2r;
        unsigned short* Wt = (wb < 128) ? Wt1 : Wt2;
        int idx = (wb & 127) * 256 + threadIdx.x;   // 0..32767
        int nn = idx >> 8;       // output col
        int kk = idx & 255;      // concat K
        float v = (kk < 128) ? Wl[(size_t)kk * ND + nn] : Wr[(size_t)(kk - 128) * ND + nn];
        Wt[(size_t)nn * KTOT + kk] = f2bf(v);
    } else {
        int e = (b - xBlocks - 256) * 256 + threadIdx.x;
        if (e < E) atomicAdd(&deg[edst[e]], 1);
    }
}

// ---------------- mean aggregation: 16 lanes/node, clamp+mask chunks of 4 ----------------
__global__ void k_aggregate_bf(const unsigned short* __restrict__ feat,
                               unsigned short* __restrict__ out,
                               const int* __restrict__ start, const int* __restrict__ deg,
                               const int* __restrict__ esrc, int n) {
    int node = (int)((blockIdx.x * (size_t)blockDim.x + threadIdx.x) >> 4);
    int l = threadIdx.x & 15;
    if (node >= n) return;
    int s = start[node];
    int d = deg[node];
    float a0 = 0, a1 = 0, a2 = 0, a3 = 0, a4 = 0, a5 = 0, a6 = 0, a7 = 0;
    const int cap = s + d - 1;           // valid when d>0 (loop guarded by j<d)
    for (int j = 0; j < d; j += 4) {
        int i0 = s + j;
        int s0 = esrc[i0];
        int s1 = esrc[min(i0 + 1, cap)];
        int s2 = esrc[min(i0 + 2, cap)];
        int s3 = esrc[min(i0 + 3, cap)];
        uint4 v0 = ((const uint4*)(feat + (size_t)s0 * ND))[l];
        uint4 v1 = ((const uint4*)(feat + (size_t)s1 * ND))[l];
        uint4 v2 = ((const uint4*)(feat + (size_t)s2 * ND))[l];
        uint4 v3 = ((const uint4*)(feat + (size_t)s3 * ND))[l];
        if (j + 1 >= d) { v1.x = v1.y = v1.z = v1.w = 0u; }
        if (j + 2 >= d) { v2.x = v2.y = v2.z = v2.w = 0u; }
        if (j + 3 >= d) { v3.x = v3.y = v3.z = v3.w = 0u; }
        a0 += bf_lo(v0.x) + bf_lo(v1.x) + bf_lo(v2.x) + bf_lo(v3.x);
        a1 += bf_hi(v0.x) + bf_hi(v1.x) + bf_hi(v2.x) + bf_hi(v3.x);
        a2 += bf_lo(v0.y) + bf_lo(v1.y) + bf_lo(v2.y) + bf_lo(v3.y);
        a3 += bf_hi(v0.y) + bf_hi(v1.y) + bf_hi(v2.y) + bf_hi(v3.y);
        a4 += bf_lo(v0.z) + bf_lo(v1.z) + bf_lo(v2.z) + bf_lo(v3.z);
        a5 += bf_hi(v0.z) + bf_hi(v1.z) + bf_hi(v2.z) + bf_hi(v3.z);
        a6 += bf_lo(v0.w) + bf_lo(v1.w) + bf_lo(v2.w) + bf_lo(v3.w);
        a7 += bf_hi(v0.w) + bf_hi(v1.w) + bf_hi(v2.w) + bf_hi(v3.w);
    }
    float inv = 1.0f / (float)max(d, 1);
    uint4 r;
    r.x = (unsigned)f2bf(a0 * inv) | ((unsigned)f2bf(a1 * inv) << 16);
    r.y = (unsigned)f2bf(a2 * inv) | ((unsigned)f2bf(a3 * inv) << 16);
    r.z = (unsigned)f2bf(a4 * inv) | ((unsigned)f2bf(a5 * inv) << 16);
    r.w = (unsigned)f2bf(a6 * inv) | ((unsigned)f2bf(a7 * inv) << 16);
    ((uint4*)(out + (size_t)node * ND))[l] = r;
}

// ---------------- MFMA GEMM layer 1 (bf16 in, bf16 out) ----------------
__launch_bounds__(256, 2)
__global__ void k_layer_mfma(const unsigned short* __restrict__ A0,
                             const unsigned short* __restrict__ A1,
                             const unsigned short* __restrict__ Wt,
                             const float* __restrict__ bias,
                             unsigned short* __restrict__ out, int n) {
    __shared__ __align__(16) unsigned short As[128 * ASTRIDE];
    __shared__ __align__(16) unsigned short Bs[128 * ASTRIDE];
    const int t = threadIdx.x;
    const int m0 = blockIdx.x * 128;
    const int wave = t >> 6, lane = t & 63;
    const int l31 = lane & 31, lhalf = lane >> 5;
    const int wm = (wave >> 1) * 64;
    const int wn = (wave & 1) * 64;

    floatx16 acc[2][2];
#pragma unroll
    for (int i = 0; i < 2; ++i)
#pragma unroll
        for (int j = 0; j < 2; ++j) acc[i][j] = (floatx16)0.0f;

    const int srow = t >> 1;
    const int skid = (t & 1) * 16;

    for (int kc = 0; kc < 8; ++kc) {
        const int k0 = kc * 32;
        {
            const unsigned short* base = (k0 < 128) ? A0 : A1;
            const int col = (k0 & 127) + skid;
            const int grow = m0 + srow;
            int4 w0 = {0, 0, 0, 0}, w1 = {0, 0, 0, 0};
            if (grow < n) {
                const int4* p = (const int4*)(base + (size_t)grow * ND + col);
                w0 = p[0]; w1 = p[1];
            }
            int4* q = (int4*)&As[srow * ASTRIDE + skid];
            q[0] = w0; q[1] = w1;
        }
        {
            const int4* p = (const int4*)(Wt + (size_t)srow * KTOT + k0 + skid);
            int4* q = (int4*)&Bs[srow * ASTRIDE + skid];
            q[0] = p[0]; q[1] = p[1];
        }
        __syncthreads();
        bf16x8 af[2][2], bfr[2][2];
#pragma unroll
        for (int mi = 0; mi < 2; ++mi)
#pragma unroll
            for (int ks = 0; ks < 2; ++ks)
                af[mi][ks] = *(const bf16x8*)&As[(wm + mi * 32 + l31) * ASTRIDE + ks * 16 + lhalf * 8];
#pragma unroll
        for (int ni = 0; ni < 2; ++ni)
#pragma unroll
            for (int ks = 0; ks < 2; ++ks)
                bfr[ni][ks] = *(const bf16x8*)&Bs[(wn + ni * 32 + l31) * ASTRIDE + ks * 16 + lhalf * 8];
#pragma unroll
        for (int mi = 0; mi < 2; ++mi)
#pragma unroll
            for (int ni = 0; ni < 2; ++ni) {
                acc[mi][ni] = __builtin_amdgcn_mfma_f32_32x32x16_bf16(af[mi][0], bfr[ni][0], acc[mi][ni], 0, 0, 0);
                acc[mi][ni] = __builtin_amdgcn_mfma_f32_32x32x16_bf16(af[mi][1], bfr[ni][1], acc[mi][ni], 0, 0, 0);
            }
        __syncthreads();
    }
    // epilogue: relu + bf16 store. C/D: col=lane&31, row=(reg&3)+8*(reg>>2)+4*(lane>>5)
#pragma unroll
    for (int mi = 0; mi < 2; ++mi)
#pragma unroll
        for (int ni = 0; ni < 2; ++ni) {
            const int c = wn + ni * 32 + l31;
            const float bv = bias[c];
#pragma unroll
            for (int reg = 0; reg < 16; ++reg) {
                const int row = m0 + wm + mi * 32 + lhalf * 4 + (reg & 3) + 8 * (reg >> 2);
                if (row < n) {
                    float v = fmaxf(acc[mi][ni][reg] + bv, 0.f);
                    out[(size_t)row * ND + c] = f2bf(v);
                }
            }
        }
}

// ---------------- MFMA GEMM layer 2 + fused head ----------------
__launch_bounds__(256, 2)
__global__ void k_layer2_head(const unsigned short* __restrict__ A0,
                              const unsigned short* __restrict__ A1,
                              const unsigned short* __restrict__ Wt,
                              const float* __restrict__ bias,
                              const float* __restrict__ Wlin,
                              const float* __restrict__ blin,
                              float* __restrict__ out, int n) {
    __shared__ __align__(16) unsigned short As[128 * ASTRIDE];
    __shared__ __align__(16) unsigned short Bs[128 * ASTRIDE];
    __shared__ float part[128][2];
    const int t = threadIdx.x;
    const int m0 = blockIdx.x * 128;
    const int wave = t >> 6, lane = t & 63;
    const int l31 = lane & 31, lhalf = lane >> 5;
    const int wm = (wave >> 1) * 64;
    const int wn = (wave & 1) * 64;

    floatx16 acc[2][2];
#pragma unroll
    for (int i = 0; i < 2; ++i)
#pragma unroll
        for (int j = 0; j < 2; ++j) acc[i][j] = (floatx16)0.0f;

    const int srow = t >> 1;
    const int skid = (t & 1) * 16;

    for (int kc = 0; kc < 8; ++kc) {
        const int k0 = kc * 32;
        {
            const unsigned short* base = (k0 < 128) ? A0 : A1;
            const int col = (k0 & 127) + skid;
            const int grow = m0 + srow;
            int4 w0 = {0, 0, 0, 0}, w1 = {0, 0, 0, 0};
            if (grow < n) {
                const int4* p = (const int4*)(base + (size_t)grow * ND + col);
                w0 = p[0]; w1 = p[1];
            }
            int4* q = (int4*)&As[srow * ASTRIDE + skid];
            q[0] = w0; q[1] = w1;
        }
        {
            const int4* p = (const int4*)(Wt + (size_t)srow * KTOT + k0 + skid);
            int4* q = (int4*)&Bs[srow * ASTRIDE + skid];
            q[0] = p[0]; q[1] = p[1];
        }
        __syncthreads();
        bf16x8 af[2][2], bfr[2][2];
#pragma unroll
        for (int mi = 0; mi < 2; ++mi)
#pragma unroll
            for (int ks = 0; ks < 2; ++ks)
                af[mi][ks] = *(const bf16x8*)&As[(wm + mi * 32 + l31) * ASTRIDE + ks * 16 + lhalf * 8];
#pragma unroll
        for (int ni = 0; ni < 2; ++ni)
#pragma unroll
            for (int ks = 0; ks < 2; ++ks)
                bfr[ni][ks] = *(const bf16x8*)&Bs[(wn + ni * 32 + l31) * ASTRIDE + ks * 16 + lhalf * 8];
#pragma unroll
        for (int mi = 0; mi < 2; ++mi)
#pragma unroll
            for (int ni = 0; ni < 2; ++ni) {
                acc[mi][ni] = __builtin_amdgcn_mfma_f32_32x32x16_bf16(af[mi][0], bfr[ni][0], acc[mi][ni], 0, 0, 0);
                acc[mi][ni] = __builtin_amdgcn_mfma_f32_32x32x16_bf16(af[mi][1], bfr[ni][1], acc[mi][ni], 0, 0, 0);
            }
        __syncthreads();
    }
    // fused epilogue: p[reg] = sum_c relu(h2[row][c]) * Wlin[c], reduced across lanes.
#pragma unroll
    for (int mi = 0; mi < 2; ++mi) {
        float p[16];
#pragma unroll
        for (int reg = 0; reg < 16; ++reg) p[reg] = 0.f;
#pragma unroll
        for (int ni = 0; ni < 2; ++ni) {
            const int c = wn + ni * 32 + l31;
            const float bv = bias[c];
            const float wv = Wlin[c];
#pragma unroll
            for (int reg = 0; reg < 16; ++reg) {
                float v = fmaxf(acc[mi][ni][reg] + bv, 0.f);
                p[reg] += v * wv;
            }
        }
#pragma unroll
        for (int reg = 0; reg < 16; ++reg) {
            float v = p[reg];
            v += __shfl_xor(v, 1);
            v += __shfl_xor(v, 2);
            v += __shfl_xor(v, 4);
            v += __shfl_xor(v, 8);
            v += __shfl_xor(v, 16);
            if (l31 == 0) {
                int rl = wm + mi * 32 + lhalf * 4 + (reg & 3) + 8 * (reg >> 2);
                part[rl][wave & 1] = v;
            }
        }
    }
    __syncthreads();
    if (t < 128) {
        int row = m0 + t;
        if (row < n) out[row] = part[t][0] + part[t][1] + blin[0];
    }
}

extern "C" void kernel_launch(void* const* d_in, const int* in_sizes, int n_in,
                              void* d_out, int out_size, void* d_ws, size_t ws_size,
                              hipStream_t stream) {
    const float* x    = (const float*)d_in[0];
    const int*   edge = (const int*)d_in[1];    // [2, E]
    const float* W1l  = (const float*)d_in[2];
    const float* b1   = (const float*)d_in[3];
    const float* W1r  = (const float*)d_in[4];
    const float* W2l  = (const float*)d_in[5];
    const float* b2   = (const float*)d_in[6];
    const float* W2r  = (const float*)d_in[7];
    const float* Wlin = (const float*)d_in[8];
    const float* blin = (const float*)d_in[9];
    float* out = (float*)d_out;

    int n = out_size;               // 100000 nodes
    int E = in_sizes[1] / 2;        // 640000 edges
    (void)n_in; (void)ws_size;

    char* ws = (char*)d_ws;
    size_t off = 0;
    auto take = [&](size_t bytes) -> char* {
        char* p = ws + off;
        off += (bytes + 255) & ~(size_t)255;
        return p;
    };
    int* deg    = (int*)take((size_t)n * 4 + 256);   // cursor rides at deg[n]
    int* cursor = deg + n;
    int* start  = (int*)take((size_t)n * 4);
    int* fill   = (int*)take((size_t)n * 4);
    int* esrc   = (int*)take((size_t)E * 4);
    unsigned short* xbf  = (unsigned short*)take((size_t)n * ND * 2);
    unsigned short* h1bf = (unsigned short*)take((size_t)n * ND * 2);
    unsigned short* agbf = (unsigned short*)take((size_t)n * ND * 2);
    unsigned short* Wt1  = (unsigned short*)take((size_t)ND * KTOT * 2);
    unsigned short* Wt2  = (unsigned short*)take((size_t)ND * KTOT * 2);

    hipMemsetAsync(deg, 0, (size_t)n * 4 + 4, stream);   // deg + cursor in one fill

    const int* esrc_in = edge;       // row 0: src
    const int* edst_in = edge + E;   // row 1: dst

    int xBlocks = (n * ND / 8 + 255) / 256;
    int cntBlocks = (E + 255) / 256;

    k_prep_count<<<xBlocks + 256 + cntBlocks, 256, 0, stream>>>(
        x, xbf, n * ND, xBlocks, W1l, W1r, Wt1, W2l, W2r, Wt2, edst_in, deg, E);
    k_offsets<<<(n + 255) / 256, 256, 0, stream>>>(deg, start, fill, cursor, n);
    k_scatter<<<(E + 255) / 256, 256, 0, stream>>>(esrc_in, edst_in, fill, esrc, E);

    int aggBlocks  = (n + 15) / 16;      // 16 nodes per 256-thread block
    int gemmBlocks = (n + 127) / 128;

    // layer 1
    k_aggregate_bf<<<aggBlocks, 256, 0, stream>>>(xbf, agbf, start, deg, esrc, n);
    k_layer_mfma<<<gemmBlocks, 256, 0, stream>>>(agbf, xbf, Wt1, b1, h1bf, n);
    // layer 2 + head (h2 never materialized)
    k_aggregate_bf<<<aggBlocks, 256, 0, stream>>>(h1bf, agbf, start, deg, esrc, n);
    k_layer2_head<<<gemmBlocks, 256, 0, stream>>>(agbf, h1bf, Wt2, b2, Wlin, blin, out, n);
}

// Round 7
// 242.050 us; speedup vs baseline: 1.4517x; 1.1638x over previous
//
#include <hip/hip_runtime.h>
#include <hip/hip_bf16.h>

// GraphSAGE 2-layer + linear head, N=100000, d=h=128, E=640000.
// R7: CSR replaced by fixed-capacity buckets (CAP=48, Poisson(6.4) max deg
//     ~24 => overflow prob ~1e-15). One fused atomic scatter both counts and
//     places edges; count/offsets passes deleted. Pipeline: memset,
//     prep(convert|weights|scatter), agg1, gemm1, agg2, gemm2+head = 6 dispatches.

#define ND 128          // feature dim
#define KTOT 256        // concat K ([agg | self])
#define ASTRIDE 40      // 32 + 8 pad (shorts)
#define CAP 48          // neighbor bucket capacity per node

typedef __bf16 bf16x8 __attribute__((ext_vector_type(8)));
typedef float floatx16 __attribute__((ext_vector_type(16)));

__device__ inline unsigned short f2bf(float f) {
    union { float f; unsigned u; } v; v.f = f;
    unsigned r = v.u + 0x7fffu + ((v.u >> 16) & 1u);   // RTNE
    return (unsigned short)(r >> 16);
}
__device__ inline float bf_lo(unsigned u) { return __uint_as_float(u << 16); }
__device__ inline float bf_hi(unsigned u) { return __uint_as_float(u & 0xffff0000u); }

// ---------------- merged prep: x->bf16 | Wt1 | Wt2 | bucket scatter ----------------
__global__ void k_prep_scatter(const float* __restrict__ x, unsigned short* __restrict__ xbf,
                               int nElems, int xBlocks,
                               const float* __restrict__ W1l, const float* __restrict__ W1r,
                               unsigned short* __restrict__ Wt1,
                               const float* __restrict__ W2l, const float* __restrict__ W2r,
                               unsigned short* __restrict__ Wt2,
                               const int* __restrict__ esrc_in, const int* __restrict__ edst_in,
                               int* __restrict__ cnt, int* __restrict__ ebuk, int E) {
    int b = blockIdx.x;
    if (b < xBlocks) {
        int i = (b * 256 + threadIdx.x) * 8;
        if (i >= nElems) return;
        float4 a = *(const float4*)(x + i);
        float4 c = *(const float4*)(x + i + 4);
        uint4 r;
        r.x = (unsigned)f2bf(a.x) | ((unsigned)f2bf(a.y) << 16);
        r.y = (unsigned)f2bf(a.z) | ((unsigned)f2bf(a.w) << 16);
        r.z = (unsigned)f2bf(c.x) | ((unsigned)f2bf(c.y) << 16);
        r.w = (unsigned)f2bf(c.z) | ((unsigned)f2bf(c.w) << 16);
        *(uint4*)(xbf + i) = r;
    } else if (b < xBlocks + 256) {
        int wb = b - xBlocks;
        const float* Wl = (wb < 128) ? W1l : W2l;
        const float* Wr = (wb < 128) ? W1r : W2r;
        unsigned short* Wt = (wb < 128) ? Wt1 : Wt2;
        int idx = (wb & 127) * 256 + threadIdx.x;   // 0..32767
        int nn = idx >> 8;       // output col
        int kk = idx & 255;      // concat K
        float v = (kk < 128) ? Wl[(size_t)kk * ND + nn] : Wr[(size_t)(kk - 128) * ND + nn];
        Wt[(size_t)nn * KTOT + kk] = f2bf(v);
    } else {
        int e = (b - xBlocks - 256) * 256 + threadIdx.x;
        if (e < E) {
            int dst = edst_in[e];
            int p = atomicAdd(&cnt[dst], 1);
            if (p < CAP) ebuk[dst * CAP + p] = esrc_in[e];
        }
    }
}

// ---------------- mean aggregation: 16 lanes/node, clamp+mask chunks of 4 ----------------
__global__ void k_aggregate_bf(const unsigned short* __restrict__ feat,
                               unsigned short* __restrict__ out,
                               const int* __restrict__ cnt,
                               const int* __restrict__ ebuk, int n) {
    int node = (int)((blockIdx.x * (size_t)blockDim.x + threadIdx.x) >> 4);
    int l = threadIdx.x & 15;
    if (node >= n) return;
    int d = cnt[node];
    int dd = min(d, CAP);
    const int* lst = ebuk + node * CAP;
    float a0 = 0, a1 = 0, a2 = 0, a3 = 0, a4 = 0, a5 = 0, a6 = 0, a7 = 0;
    const int capi = dd - 1;             // valid when dd>0 (loop guarded by j<dd)
    for (int j = 0; j < dd; j += 4) {
        int s0 = lst[j];
        int s1 = lst[min(j + 1, capi)];
        int s2 = lst[min(j + 2, capi)];
        int s3 = lst[min(j + 3, capi)];
        uint4 v0 = ((const uint4*)(feat + (size_t)s0 * ND))[l];
        uint4 v1 = ((const uint4*)(feat + (size_t)s1 * ND))[l];
        uint4 v2 = ((const uint4*)(feat + (size_t)s2 * ND))[l];
        uint4 v3 = ((const uint4*)(feat + (size_t)s3 * ND))[l];
        if (j + 1 >= dd) { v1.x = v1.y = v1.z = v1.w = 0u; }
        if (j + 2 >= dd) { v2.x = v2.y = v2.z = v2.w = 0u; }
        if (j + 3 >= dd) { v3.x = v3.y = v3.z = v3.w = 0u; }
        a0 += bf_lo(v0.x) + bf_lo(v1.x) + bf_lo(v2.x) + bf_lo(v3.x);
        a1 += bf_hi(v0.x) + bf_hi(v1.x) + bf_hi(v2.x) + bf_hi(v3.x);
        a2 += bf_lo(v0.y) + bf_lo(v1.y) + bf_lo(v2.y) + bf_lo(v3.y);
        a3 += bf_hi(v0.y) + bf_hi(v1.y) + bf_hi(v2.y) + bf_hi(v3.y);
        a4 += bf_lo(v0.z) + bf_lo(v1.z) + bf_lo(v2.z) + bf_lo(v3.z);
        a5 += bf_hi(v0.z) + bf_hi(v1.z) + bf_hi(v2.z) + bf_hi(v3.z);
        a6 += bf_lo(v0.w) + bf_lo(v1.w) + bf_lo(v2.w) + bf_lo(v3.w);
        a7 += bf_hi(v0.w) + bf_hi(v1.w) + bf_hi(v2.w) + bf_hi(v3.w);
    }
    float inv = 1.0f / (float)max(d, 1);
    uint4 r;
    r.x = (unsigned)f2bf(a0 * inv) | ((unsigned)f2bf(a1 * inv) << 16);
    r.y = (unsigned)f2bf(a2 * inv) | ((unsigned)f2bf(a3 * inv) << 16);
    r.z = (unsigned)f2bf(a4 * inv) | ((unsigned)f2bf(a5 * inv) << 16);
    r.w = (unsigned)f2bf(a6 * inv) | ((unsigned)f2bf(a7 * inv) << 16);
    ((uint4*)(out + (size_t)node * ND))[l] = r;
}

// ---------------- MFMA GEMM layer 1 (bf16 in, bf16 out) ----------------
__launch_bounds__(256, 2)
__global__ void k_layer_mfma(const unsigned short* __restrict__ A0,
                             const unsigned short* __restrict__ A1,
                             const unsigned short* __restrict__ Wt,
                             const float* __restrict__ bias,
                             unsigned short* __restrict__ out, int n) {
    __shared__ __align__(16) unsigned short As[128 * ASTRIDE];
    __shared__ __align__(16) unsigned short Bs[128 * ASTRIDE];
    const int t = threadIdx.x;
    const int m0 = blockIdx.x * 128;
    const int wave = t >> 6, lane = t & 63;
    const int l31 = lane & 31, lhalf = lane >> 5;
    const int wm = (wave >> 1) * 64;
    const int wn = (wave & 1) * 64;

    floatx16 acc[2][2];
#pragma unroll
    for (int i = 0; i < 2; ++i)
#pragma unroll
        for (int j = 0; j < 2; ++j) acc[i][j] = (floatx16)0.0f;

    const int srow = t >> 1;
    const int skid = (t & 1) * 16;

    for (int kc = 0; kc < 8; ++kc) {
        const int k0 = kc * 32;
        {
            const unsigned short* base = (k0 < 128) ? A0 : A1;
            const int col = (k0 & 127) + skid;
            const int grow = m0 + srow;
            int4 w0 = {0, 0, 0, 0}, w1 = {0, 0, 0, 0};
            if (grow < n) {
                const int4* p = (const int4*)(base + (size_t)grow * ND + col);
                w0 = p[0]; w1 = p[1];
            }
            int4* q = (int4*)&As[srow * ASTRIDE + skid];
            q[0] = w0; q[1] = w1;
        }
        {
            const int4* p = (const int4*)(Wt + (size_t)srow * KTOT + k0 + skid);
            int4* q = (int4*)&Bs[srow * ASTRIDE + skid];
            q[0] = p[0]; q[1] = p[1];
        }
        __syncthreads();
        bf16x8 af[2][2], bfr[2][2];
#pragma unroll
        for (int mi = 0; mi < 2; ++mi)
#pragma unroll
            for (int ks = 0; ks < 2; ++ks)
                af[mi][ks] = *(const bf16x8*)&As[(wm + mi * 32 + l31) * ASTRIDE + ks * 16 + lhalf * 8];
#pragma unroll
        for (int ni = 0; ni < 2; ++ni)
#pragma unroll
            for (int ks = 0; ks < 2; ++ks)
                bfr[ni][ks] = *(const bf16x8*)&Bs[(wn + ni * 32 + l31) * ASTRIDE + ks * 16 + lhalf * 8];
#pragma unroll
        for (int mi = 0; mi < 2; ++mi)
#pragma unroll
            for (int ni = 0; ni < 2; ++ni) {
                acc[mi][ni] = __builtin_amdgcn_mfma_f32_32x32x16_bf16(af[mi][0], bfr[ni][0], acc[mi][ni], 0, 0, 0);
                acc[mi][ni] = __builtin_amdgcn_mfma_f32_32x32x16_bf16(af[mi][1], bfr[ni][1], acc[mi][ni], 0, 0, 0);
            }
        __syncthreads();
    }
    // epilogue: relu + bf16 store. C/D: col=lane&31, row=(reg&3)+8*(reg>>2)+4*(lane>>5)
#pragma unroll
    for (int mi = 0; mi < 2; ++mi)
#pragma unroll
        for (int ni = 0; ni < 2; ++ni) {
            const int c = wn + ni * 32 + l31;
            const float bv = bias[c];
#pragma unroll
            for (int reg = 0; reg < 16; ++reg) {
                const int row = m0 + wm + mi * 32 + lhalf * 4 + (reg & 3) + 8 * (reg >> 2);
                if (row < n) {
                    float v = fmaxf(acc[mi][ni][reg] + bv, 0.f);
                    out[(size_t)row * ND + c] = f2bf(v);
                }
            }
        }
}

// ---------------- MFMA GEMM layer 2 + fused head ----------------
__launch_bounds__(256, 2)
__global__ void k_layer2_head(const unsigned short* __restrict__ A0,
                              const unsigned short* __restrict__ A1,
                              const unsigned short* __restrict__ Wt,
                              const float* __restrict__ bias,
                              const float* __restrict__ Wlin,
                              const float* __restrict__ blin,
                              float* __restrict__ out, int n) {
    __shared__ __align__(16) unsigned short As[128 * ASTRIDE];
    __shared__ __align__(16) unsigned short Bs[128 * ASTRIDE];
    __shared__ float part[128][2];
    const int t = threadIdx.x;
    const int m0 = blockIdx.x * 128;
    const int wave = t >> 6, lane = t & 63;
    const int l31 = lane & 31, lhalf = lane >> 5;
    const int wm = (wave >> 1) * 64;
    const int wn = (wave & 1) * 64;

    floatx16 acc[2][2];
#pragma unroll
    for (int i = 0; i < 2; ++i)
#pragma unroll
        for (int j = 0; j < 2; ++j) acc[i][j] = (floatx16)0.0f;

    const int srow = t >> 1;
    const int skid = (t & 1) * 16;

    for (int kc = 0; kc < 8; ++kc) {
        const int k0 = kc * 32;
        {
            const unsigned short* base = (k0 < 128) ? A0 : A1;
            const int col = (k0 & 127) + skid;
            const int grow = m0 + srow;
            int4 w0 = {0, 0, 0, 0}, w1 = {0, 0, 0, 0};
            if (grow < n) {
                const int4* p = (const int4*)(base + (size_t)grow * ND + col);
                w0 = p[0]; w1 = p[1];
            }
            int4* q = (int4*)&As[srow * ASTRIDE + skid];
            q[0] = w0; q[1] = w1;
        }
        {
            const int4* p = (const int4*)(Wt + (size_t)srow * KTOT + k0 + skid);
            int4* q = (int4*)&Bs[srow * ASTRIDE + skid];
            q[0] = p[0]; q[1] = p[1];
        }
        __syncthreads();
        bf16x8 af[2][2], bfr[2][2];
#pragma unroll
        for (int mi = 0; mi < 2; ++mi)
#pragma unroll
            for (int ks = 0; ks < 2; ++ks)
                af[mi][ks] = *(const bf16x8*)&As[(wm + mi * 32 + l31) * ASTRIDE + ks * 16 + lhalf * 8];
#pragma unroll
        for (int ni = 0; ni < 2; ++ni)
#pragma unroll
            for (int ks = 0; ks < 2; ++ks)
                bfr[ni][ks] = *(const bf16x8*)&Bs[(wn + ni * 32 + l31) * ASTRIDE + ks * 16 + lhalf * 8];
#pragma unroll
        for (int mi = 0; mi < 2; ++mi)
#pragma unroll
            for (int ni = 0; ni < 2; ++ni) {
                acc[mi][ni] = __builtin_amdgcn_mfma_f32_32x32x16_bf16(af[mi][0], bfr[ni][0], acc[mi][ni], 0, 0, 0);
                acc[mi][ni] = __builtin_amdgcn_mfma_f32_32x32x16_bf16(af[mi][1], bfr[ni][1], acc[mi][ni], 0, 0, 0);
            }
        __syncthreads();
    }
    // fused epilogue: p[reg] = sum_c relu(h2[row][c]) * Wlin[c], reduced across lanes.
#pragma unroll
    for (int mi = 0; mi < 2; ++mi) {
        float p[16];
#pragma unroll
        for (int reg = 0; reg < 16; ++reg) p[reg] = 0.f;
#pragma unroll
        for (int ni = 0; ni < 2; ++ni) {
            const int c = wn + ni * 32 + l31;
            const float bv = bias[c];
            const float wv = Wlin[c];
#pragma unroll
            for (int reg = 0; reg < 16; ++reg) {
                float v = fmaxf(acc[mi][ni][reg] + bv, 0.f);
                p[reg] += v * wv;
            }
        }
#pragma unroll
        for (int reg = 0; reg < 16; ++reg) {
            float v = p[reg];
            v += __shfl_xor(v, 1);
            v += __shfl_xor(v, 2);
            v += __shfl_xor(v, 4);
            v += __shfl_xor(v, 8);
            v += __shfl_xor(v, 16);
            if (l31 == 0) {
                int rl = wm + mi * 32 + lhalf * 4 + (reg & 3) + 8 * (reg >> 2);
                part[rl][wave & 1] = v;
            }
        }
    }
    __syncthreads();
    if (t < 128) {
        int row = m0 + t;
        if (row < n) out[row] = part[t][0] + part[t][1] + blin[0];
    }
}

extern "C" void kernel_launch(void* const* d_in, const int* in_sizes, int n_in,
                              void* d_out, int out_size, void* d_ws, size_t ws_size,
                              hipStream_t stream) {
    const float* x    = (const float*)d_in[0];
    const int*   edge = (const int*)d_in[1];    // [2, E]
    const float* W1l  = (const float*)d_in[2];
    const float* b1   = (const float*)d_in[3];
    const float* W1r  = (const float*)d_in[4];
    const float* W2l  = (const float*)d_in[5];
    const float* b2   = (const float*)d_in[6];
    const float* W2r  = (const float*)d_in[7];
    const float* Wlin = (const float*)d_in[8];
    const float* blin = (const float*)d_in[9];
    float* out = (float*)d_out;

    int n = out_size;               // 100000 nodes
    int E = in_sizes[1] / 2;        // 640000 edges
    (void)n_in; (void)ws_size;

    char* ws = (char*)d_ws;
    size_t off = 0;
    auto take = [&](size_t bytes) -> char* {
        char* p = ws + off;
        off += (bytes + 255) & ~(size_t)255;
        return p;
    };
    int* cnt    = (int*)take((size_t)n * 4);
    int* ebuk   = (int*)take((size_t)n * CAP * 4);
    unsigned short* xbf  = (unsigned short*)take((size_t)n * ND * 2);
    unsigned short* h1bf = (unsigned short*)take((size_t)n * ND * 2);
    unsigned short* agbf = (unsigned short*)take((size_t)n * ND * 2);
    unsigned short* Wt1  = (unsigned short*)take((size_t)ND * KTOT * 2);
    unsigned short* Wt2  = (unsigned short*)take((size_t)ND * KTOT * 2);

    hipMemsetAsync(cnt, 0, (size_t)n * 4, stream);

    const int* esrc_in = edge;       // row 0: src
    const int* edst_in = edge + E;   // row 1: dst

    int xBlocks = (n * ND / 8 + 255) / 256;
    int scatBlocks = (E + 255) / 256;

    k_prep_scatter<<<xBlocks + 256 + scatBlocks, 256, 0, stream>>>(
        x, xbf, n * ND, xBlocks, W1l, W1r, Wt1, W2l, W2r, Wt2,
        esrc_in, edst_in, cnt, ebuk, E);

    int aggBlocks  = (n + 15) / 16;      // 16 nodes per 256-thread block
    int gemmBlocks = (n + 127) / 128;

    // layer 1
    k_aggregate_bf<<<aggBlocks, 256, 0, stream>>>(xbf, agbf, cnt, ebuk, n);
    k_layer_mfma<<<gemmBlocks, 256, 0, stream>>>(agbf, xbf, Wt1, b1, h1bf, n);
    // layer 2 + head (h2 never materialized)
    k_aggregate_bf<<<aggBlocks, 256, 0, stream>>>(h1bf, agbf, cnt, ebuk, n);
    k_layer2_head<<<gemmBlocks, 256, 0, stream>>>(agbf, h1bf, Wt2, b2, Wlin, blin, out, n);
}

// Round 8
// 233.237 us; speedup vs baseline: 1.5066x; 1.0378x over previous
//
#include <hip/hip_runtime.h>
#include <hip/hip_bf16.h>

// GraphSAGE 2-layer + linear head, N=100000, d=h=128, E=640000.
// R8: prep kernel flattened to THREAD-level job fusion — every thread does
//     up to 3 independent jobs (edge scatter, x->bf16 convert, weight prep)
//     so the scatter's ~600cyc atomic round trip overlaps the convert's HBM
//     loads instead of running as a separate sequential grid phase.
//     Pipeline: memset(cnt), prep_all, agg1, gemm1, agg2, gemm2+head.

#define ND 128          // feature dim
#define KTOT 256        // concat K ([agg | self])
#define ASTRIDE 40      // 32 + 8 pad (shorts)
#define CAP 48          // neighbor bucket capacity per node

typedef __bf16 bf16x8 __attribute__((ext_vector_type(8)));
typedef float floatx16 __attribute__((ext_vector_type(16)));

__device__ inline unsigned short f2bf(float f) {
    union { float f; unsigned u; } v; v.f = f;
    unsigned r = v.u + 0x7fffu + ((v.u >> 16) & 1u);   // RTNE
    return (unsigned short)(r >> 16);
}
__device__ inline float bf_lo(unsigned u) { return __uint_as_float(u << 16); }
__device__ inline float bf_hi(unsigned u) { return __uint_as_float(u & 0xffff0000u); }

// ---------------- prep: per-THREAD fusion of scatter | convert | weights ----------------
__global__ void k_prep_all(const float* __restrict__ x, unsigned short* __restrict__ xbf,
                           int nElems,
                           const float* __restrict__ W1l, const float* __restrict__ W1r,
                           unsigned short* __restrict__ Wt1,
                           const float* __restrict__ W2l, const float* __restrict__ W2r,
                           unsigned short* __restrict__ Wt2,
                           const int* __restrict__ esrc_in, const int* __restrict__ edst_in,
                           int* __restrict__ cnt, int* __restrict__ ebuk, int E) {
    const int tid = blockIdx.x * 256 + threadIdx.x;

    // --- job 1: edge scatter (issue the long-latency atomic FIRST) ---
    int edstv = 0, esrcv = 0, p = -1;
    if (tid < E) {
        edstv = edst_in[tid];
        esrcv = esrc_in[tid];
        p = atomicAdd(&cnt[edstv], 1);
    }

    // --- job 2: x -> bf16 convert (HBM-bound; overlaps the atomic) ---
    const int i = tid * 8;
    if (i < nElems) {
        float4 a = *(const float4*)(x + i);
        float4 c = *(const float4*)(x + i + 4);
        uint4 r;
        r.x = (unsigned)f2bf(a.x) | ((unsigned)f2bf(a.y) << 16);
        r.y = (unsigned)f2bf(a.z) | ((unsigned)f2bf(a.w) << 16);
        r.z = (unsigned)f2bf(c.x) | ((unsigned)f2bf(c.y) << 16);
        r.w = (unsigned)f2bf(c.z) | ((unsigned)f2bf(c.w) << 16);
        *(uint4*)(xbf + i) = r;
    }

    // --- job 3: weight transpose+convert (tiny) ---
    if (tid < 2 * KTOT * ND) {
        const int half = tid >> 15;            // 0 -> layer1, 1 -> layer2
        const int idx = tid & 32767;
        const int nn = idx >> 8;               // output col
        const int kk = idx & 255;              // concat K
        const float* Wl = half ? W2l : W1l;
        const float* Wr = half ? W2r : W1r;
        unsigned short* Wt = half ? Wt2 : Wt1;
        float v = (kk < 128) ? Wl[(size_t)kk * ND + nn] : Wr[(size_t)(kk - 128) * ND + nn];
        Wt[(size_t)nn * KTOT + kk] = f2bf(v);
    }

    // --- job 1 completion: dependent scatter store ---
    if (p >= 0 && p < CAP) ebuk[edstv * CAP + p] = esrcv;
}

// ---------------- mean aggregation: 16 lanes/node, clamp+mask chunks of 4 ----------------
__global__ void k_aggregate_bf(const unsigned short* __restrict__ feat,
                               unsigned short* __restrict__ out,
                               const int* __restrict__ cnt,
                               const int* __restrict__ ebuk, int n) {
    int node = (int)((blockIdx.x * (size_t)blockDim.x + threadIdx.x) >> 4);
    int l = threadIdx.x & 15;
    if (node >= n) return;
    int d = cnt[node];
    int dd = min(d, CAP);
    const int* lst = ebuk + node * CAP;
    float a0 = 0, a1 = 0, a2 = 0, a3 = 0, a4 = 0, a5 = 0, a6 = 0, a7 = 0;
    const int capi = dd - 1;             // valid when dd>0 (loop guarded by j<dd)
    for (int j = 0; j < dd; j += 4) {
        int s0 = lst[j];
        int s1 = lst[min(j + 1, capi)];
        int s2 = lst[min(j + 2, capi)];
        int s3 = lst[min(j + 3, capi)];
        uint4 v0 = ((const uint4*)(feat + (size_t)s0 * ND))[l];
        uint4 v1 = ((const uint4*)(feat + (size_t)s1 * ND))[l];
        uint4 v2 = ((const uint4*)(feat + (size_t)s2 * ND))[l];
        uint4 v3 = ((const uint4*)(feat + (size_t)s3 * ND))[l];
        if (j + 1 >= dd) { v1.x = v1.y = v1.z = v1.w = 0u; }
        if (j + 2 >= dd) { v2.x = v2.y = v2.z = v2.w = 0u; }
        if (j + 3 >= dd) { v3.x = v3.y = v3.z = v3.w = 0u; }
        a0 += bf_lo(v0.x) + bf_lo(v1.x) + bf_lo(v2.x) + bf_lo(v3.x);
        a1 += bf_hi(v0.x) + bf_hi(v1.x) + bf_hi(v2.x) + bf_hi(v3.x);
        a2 += bf_lo(v0.y) + bf_lo(v1.y) + bf_lo(v2.y) + bf_lo(v3.y);
        a3 += bf_hi(v0.y) + bf_hi(v1.y) + bf_hi(v2.y) + bf_hi(v3.y);
        a4 += bf_lo(v0.z) + bf_lo(v1.z) + bf_lo(v2.z) + bf_lo(v3.z);
        a5 += bf_hi(v0.z) + bf_hi(v1.z) + bf_hi(v2.z) + bf_hi(v3.z);
        a6 += bf_lo(v0.w) + bf_lo(v1.w) + bf_lo(v2.w) + bf_lo(v3.w);
        a7 += bf_hi(v0.w) + bf_hi(v1.w) + bf_hi(v2.w) + bf_hi(v3.w);
    }
    float inv = 1.0f / (float)max(d, 1);
    uint4 r;
    r.x = (unsigned)f2bf(a0 * inv) | ((unsigned)f2bf(a1 * inv) << 16);
    r.y = (unsigned)f2bf(a2 * inv) | ((unsigned)f2bf(a3 * inv) << 16);
    r.z = (unsigned)f2bf(a4 * inv) | ((unsigned)f2bf(a5 * inv) << 16);
    r.w = (unsigned)f2bf(a6 * inv) | ((unsigned)f2bf(a7 * inv) << 16);
    ((uint4*)(out + (size_t)node * ND))[l] = r;
}

// ---------------- MFMA GEMM layer 1 (bf16 in, bf16 out) ----------------
__launch_bounds__(256, 2)
__global__ void k_layer_mfma(const unsigned short* __restrict__ A0,
                             const unsigned short* __restrict__ A1,
                             const unsigned short* __restrict__ Wt,
                             const float* __restrict__ bias,
                             unsigned short* __restrict__ out, int n) {
    __shared__ __align__(16) unsigned short As[128 * ASTRIDE];
    __shared__ __align__(16) unsigned short Bs[128 * ASTRIDE];
    const int t = threadIdx.x;
    const int m0 = blockIdx.x * 128;
    const int wave = t >> 6, lane = t & 63;
    const int l31 = lane & 31, lhalf = lane >> 5;
    const int wm = (wave >> 1) * 64;
    const int wn = (wave & 1) * 64;

    floatx16 acc[2][2];
#pragma unroll
    for (int i = 0; i < 2; ++i)
#pragma unroll
        for (int j = 0; j < 2; ++j) acc[i][j] = (floatx16)0.0f;

    const int srow = t >> 1;
    const int skid = (t & 1) * 16;

    for (int kc = 0; kc < 8; ++kc) {
        const int k0 = kc * 32;
        {
            const unsigned short* base = (k0 < 128) ? A0 : A1;
            const int col = (k0 & 127) + skid;
            const int grow = m0 + srow;
            int4 w0 = {0, 0, 0, 0}, w1 = {0, 0, 0, 0};
            if (grow < n) {
                const int4* p = (const int4*)(base + (size_t)grow * ND + col);
                w0 = p[0]; w1 = p[1];
            }
            int4* q = (int4*)&As[srow * ASTRIDE + skid];
            q[0] = w0; q[1] = w1;
        }
        {
            const int4* p = (const int4*)(Wt + (size_t)srow * KTOT + k0 + skid);
            int4* q = (int4*)&Bs[srow * ASTRIDE + skid];
            q[0] = p[0]; q[1] = p[1];
        }
        __syncthreads();
        bf16x8 af[2][2], bfr[2][2];
#pragma unroll
        for (int mi = 0; mi < 2; ++mi)
#pragma unroll
            for (int ks = 0; ks < 2; ++ks)
                af[mi][ks] = *(const bf16x8*)&As[(wm + mi * 32 + l31) * ASTRIDE + ks * 16 + lhalf * 8];
#pragma unroll
        for (int ni = 0; ni < 2; ++ni)
#pragma unroll
            for (int ks = 0; ks < 2; ++ks)
                bfr[ni][ks] = *(const bf16x8*)&Bs[(wn + ni * 32 + l31) * ASTRIDE + ks * 16 + lhalf * 8];
#pragma unroll
        for (int mi = 0; mi < 2; ++mi)
#pragma unroll
            for (int ni = 0; ni < 2; ++ni) {
                acc[mi][ni] = __builtin_amdgcn_mfma_f32_32x32x16_bf16(af[mi][0], bfr[ni][0], acc[mi][ni], 0, 0, 0);
                acc[mi][ni] = __builtin_amdgcn_mfma_f32_32x32x16_bf16(af[mi][1], bfr[ni][1], acc[mi][ni], 0, 0, 0);
            }
        __syncthreads();
    }
    // epilogue: relu + bf16 store. C/D: col=lane&31, row=(reg&3)+8*(reg>>2)+4*(lane>>5)
#pragma unroll
    for (int mi = 0; mi < 2; ++mi)
#pragma unroll
        for (int ni = 0; ni < 2; ++ni) {
            const int c = wn + ni * 32 + l31;
            const float bv = bias[c];
#pragma unroll
            for (int reg = 0; reg < 16; ++reg) {
                const int row = m0 + wm + mi * 32 + lhalf * 4 + (reg & 3) + 8 * (reg >> 2);
                if (row < n) {
                    float v = fmaxf(acc[mi][ni][reg] + bv, 0.f);
                    out[(size_t)row * ND + c] = f2bf(v);
                }
            }
        }
}

// ---------------- MFMA GEMM layer 2 + fused head ----------------
__launch_bounds__(256, 2)
__global__ void k_layer2_head(const unsigned short* __restrict__ A0,
                              const unsigned short* __restrict__ A1,
                              const unsigned short* __restrict__ Wt,
                              const float* __restrict__ bias,
                              const float* __restrict__ Wlin,
                              const float* __restrict__ blin,
                              float* __restrict__ out, int n) {
    __shared__ __align__(16) unsigned short As[128 * ASTRIDE];
    __shared__ __align__(16) unsigned short Bs[128 * ASTRIDE];
    __shared__ float part[128][2];
    const int t = threadIdx.x;
    const int m0 = blockIdx.x * 128;
    const int wave = t >> 6, lane = t & 63;
    const int l31 = lane & 31, lhalf = lane >> 5;
    const int wm = (wave >> 1) * 64;
    const int wn = (wave & 1) * 64;

    floatx16 acc[2][2];
#pragma unroll
    for (int i = 0; i < 2; ++i)
#pragma unroll
        for (int j = 0; j < 2; ++j) acc[i][j] = (floatx16)0.0f;

    const int srow = t >> 1;
    const int skid = (t & 1) * 16;

    for (int kc = 0; kc < 8; ++kc) {
        const int k0 = kc * 32;
        {
            const unsigned short* base = (k0 < 128) ? A0 : A1;
            const int col = (k0 & 127) + skid;
            const int grow = m0 + srow;
            int4 w0 = {0, 0, 0, 0}, w1 = {0, 0, 0, 0};
            if (grow < n) {
                const int4* p = (const int4*)(base + (size_t)grow * ND + col);
                w0 = p[0]; w1 = p[1];
            }
            int4* q = (int4*)&As[srow * ASTRIDE + skid];
            q[0] = w0; q[1] = w1;
        }
        {
            const int4* p = (const int4*)(Wt + (size_t)srow * KTOT + k0 + skid);
            int4* q = (int4*)&Bs[srow * ASTRIDE + skid];
            q[0] = p[0]; q[1] = p[1];
        }
        __syncthreads();
        bf16x8 af[2][2], bfr[2][2];
#pragma unroll
        for (int mi = 0; mi < 2; ++mi)
#pragma unroll
            for (int ks = 0; ks < 2; ++ks)
                af[mi][ks] = *(const bf16x8*)&As[(wm + mi * 32 + l31) * ASTRIDE + ks * 16 + lhalf * 8];
#pragma unroll
        for (int ni = 0; ni < 2; ++ni)
#pragma unroll
            for (int ks = 0; ks < 2; ++ks)
                bfr[ni][ks] = *(const bf16x8*)&Bs[(wn + ni * 32 + l31) * ASTRIDE + ks * 16 + lhalf * 8];
#pragma unroll
        for (int mi = 0; mi < 2; ++mi)
#pragma unroll
            for (int ni = 0; ni < 2; ++ni) {
                acc[mi][ni] = __builtin_amdgcn_mfma_f32_32x32x16_bf16(af[mi][0], bfr[ni][0], acc[mi][ni], 0, 0, 0);
                acc[mi][ni] = __builtin_amdgcn_mfma_f32_32x32x16_bf16(af[mi][1], bfr[ni][1], acc[mi][ni], 0, 0, 0);
            }
        __syncthreads();
    }
    // fused epilogue: p[reg] = sum_c relu(h2[row][c]) * Wlin[c], reduced across lanes.
#pragma unroll
    for (int mi = 0; mi < 2; ++mi) {
        float p[16];
#pragma unroll
        for (int reg = 0; reg < 16; ++reg) p[reg] = 0.f;
#pragma unroll
        for (int ni = 0; ni < 2; ++ni) {
            const int c = wn + ni * 32 + l31;
            const float bv = bias[c];
            const float wv = Wlin[c];
#pragma unroll
            for (int reg = 0; reg < 16; ++reg) {
                float v = fmaxf(acc[mi][ni][reg] + bv, 0.f);
                p[reg] += v * wv;
            }
        }
#pragma unroll
        for (int reg = 0; reg < 16; ++reg) {
            float v = p[reg];
            v += __shfl_xor(v, 1);
            v += __shfl_xor(v, 2);
            v += __shfl_xor(v, 4);
            v += __shfl_xor(v, 8);
            v += __shfl_xor(v, 16);
            if (l31 == 0) {
                int rl = wm + mi * 32 + lhalf * 4 + (reg & 3) + 8 * (reg >> 2);
                part[rl][wave & 1] = v;
            }
        }
    }
    __syncthreads();
    if (t < 128) {
        int row = m0 + t;
        if (row < n) out[row] = part[t][0] + part[t][1] + blin[0];
    }
}

extern "C" void kernel_launch(void* const* d_in, const int* in_sizes, int n_in,
                              void* d_out, int out_size, void* d_ws, size_t ws_size,
                              hipStream_t stream) {
    const float* x    = (const float*)d_in[0];
    const int*   edge = (const int*)d_in[1];    // [2, E]
    const float* W1l  = (const float*)d_in[2];
    const float* b1   = (const float*)d_in[3];
    const float* W1r  = (const float*)d_in[4];
    const float* W2l  = (const float*)d_in[5];
    const float* b2   = (const float*)d_in[6];
    const float* W2r  = (const float*)d_in[7];
    const float* Wlin = (const float*)d_in[8];
    const float* blin = (const float*)d_in[9];
    float* out = (float*)d_out;

    int n = out_size;               // 100000 nodes
    int E = in_sizes[1] / 2;        // 640000 edges
    (void)n_in; (void)ws_size;

    char* ws = (char*)d_ws;
    size_t off = 0;
    auto take = [&](size_t bytes) -> char* {
        char* p = ws + off;
        off += (bytes + 255) & ~(size_t)255;
        return p;
    };
    int* cnt    = (int*)take((size_t)n * 4);
    int* ebuk   = (int*)take((size_t)n * CAP * 4);
    unsigned short* xbf  = (unsigned short*)take((size_t)n * ND * 2);
    unsigned short* h1bf = (unsigned short*)take((size_t)n * ND * 2);
    unsigned short* agbf = (unsigned short*)take((size_t)n * ND * 2);
    unsigned short* Wt1  = (unsigned short*)take((size_t)ND * KTOT * 2);
    unsigned short* Wt2  = (unsigned short*)take((size_t)ND * KTOT * 2);

    hipMemsetAsync(cnt, 0, (size_t)n * 4, stream);

    const int* esrc_in = edge;       // row 0: src
    const int* edst_in = edge + E;   // row 1: dst

    int nElems = n * ND;                         // 12.8M
    int prepBlocks = (nElems / 8 + 255) / 256;   // 6250 — covers E and weight jobs too

    k_prep_all<<<prepBlocks, 256, 0, stream>>>(
        x, xbf, nElems, W1l, W1r, Wt1, W2l, W2r, Wt2,
        esrc_in, edst_in, cnt, ebuk, E);

    int aggBlocks  = (n + 15) / 16;      // 16 nodes per 256-thread block
    int gemmBlocks = (n + 127) / 128;

    // layer 1
    k_aggregate_bf<<<aggBlocks, 256, 0, stream>>>(xbf, agbf, cnt, ebuk, n);
    k_layer_mfma<<<gemmBlocks, 256, 0, stream>>>(agbf, xbf, Wt1, b1, h1bf, n);
    // layer 2 + head (h2 never materialized)
    k_aggregate_bf<<<aggBlocks, 256, 0, stream>>>(h1bf, agbf, cnt, ebuk, n);
    k_layer2_head<<<gemmBlocks, 256, 0, stream>>>(agbf, h1bf, Wt2, b2, Wlin, blin, out, n);
}